// Round 1
// baseline (344.806 us; speedup 1.0000x reference)
//
#include <hip/hip_runtime.h>

typedef int i32x4 __attribute__((ext_vector_type(4)));

#define B_DIM   4096
#define IN_DIM  4096
#define OUT_DIM 4096
#define KPAD    4160        // 65 * 64, covers 4097 augmented K with zero pad
#define NKT     (KPAD / 64) // 65 K-tiles
#define C16     (KPAD / 16) // 260 16-byte chunks per row

// ---------------------------------------------------------------------------
// Quantize f32 -> int8 (symmetric, round-half-even to match jnp.round),
// writing the augmented+padded [nrows][KPAD] int8 matrix.
//   col <  IN_DIM : q = rint(clip(x,-c,c)*scale)
//   col == IN_DIM : augmented column (1.0 for activations, bias for weights)
//   col >  IN_DIM : 0 (zero pad, contributes nothing to the i8 dot product)
// ---------------------------------------------------------------------------
__global__ __launch_bounds__(256) void quant_kernel(
    const float* __restrict__ x, const float* __restrict__ aug,
    signed char* __restrict__ q, float clip, float scale, int nrows)
{
    int idx = blockIdx.x * 256 + threadIdx.x;
    int row = idx / C16;
    int c16 = idx - row * C16;
    if (row >= nrows) return;

    signed char o[16] __attribute__((aligned(16)));
    if (c16 < IN_DIM / 16) {
        const float4* p = reinterpret_cast<const float4*>(
            x + (size_t)row * IN_DIM + (size_t)c16 * 16);
#pragma unroll
        for (int j = 0; j < 4; ++j) {
            float4 v = p[j];
            o[j*4+0] = (signed char)(int)rintf(fminf(fmaxf(v.x, -clip), clip) * scale);
            o[j*4+1] = (signed char)(int)rintf(fminf(fmaxf(v.y, -clip), clip) * scale);
            o[j*4+2] = (signed char)(int)rintf(fminf(fmaxf(v.z, -clip), clip) * scale);
            o[j*4+3] = (signed char)(int)rintf(fminf(fmaxf(v.w, -clip), clip) * scale);
        }
    } else if (c16 == IN_DIM / 16) {
        float av = aug ? aug[row] : 1.0f;
#pragma unroll
        for (int j = 0; j < 16; ++j) o[j] = 0;
        o[0] = (signed char)(int)rintf(fminf(fmaxf(av, -clip), clip) * scale);
    } else {
#pragma unroll
        for (int j = 0; j < 16; ++j) o[j] = 0;
    }
    *reinterpret_cast<i32x4*>(q + (size_t)row * KPAD + (size_t)c16 * 16) =
        *reinterpret_cast<const i32x4*>(o);
}

// ---------------------------------------------------------------------------
// i8 GEMM: out[b][o] = (qx[b][:] . qw[o][:]) / (31.75*127) + 0.01*noise[b][o]
// 128x128 tile, BK=64, 4 waves (2x2), mfma_i32_16x16x64_i8.
// NT layout: both operands K-contiguous -> fragments are contiguous 16B reads.
// LDS slot swizzle: stored_slot = src_slot ^ ((row>>1)&3)  (involution),
// applied by pre-swizzling the global source address (global_load_lds writes
// linearly: wave-uniform LDS base + lane*16).
// ---------------------------------------------------------------------------
__global__ __launch_bounds__(256) void gemm_i8_kernel(
    const signed char* __restrict__ A,   // qx [B_DIM][KPAD]
    const signed char* __restrict__ Bq,  // qw [OUT_DIM][KPAD]
    const float* __restrict__ noise,
    float* __restrict__ out)
{
    __shared__ signed char As[128 * 64];
    __shared__ signed char Bs[128 * 64];

    const int tid = threadIdx.x;
    const int w = tid >> 6;
    const int l = tid & 63;

    // bijective XCD swizzle (1024 blocks % 8 == 0)
    const int bid = blockIdx.x;
    const int swz = (bid & 7) * 128 + (bid >> 3);
    const int brow = swz >> 5;   // 0..31
    const int bcol = swz & 31;   // 0..31

    const int wrow = w >> 1;     // 0..1
    const int wcol = w & 1;      // 0..1

    i32x4 acc[4][4];
#pragma unroll
    for (int m = 0; m < 4; ++m)
#pragma unroll
        for (int n = 0; n < 4; ++n) acc[m][n] = (i32x4)(0);

    const int crow = l >> 2;   // staging: row within 16-row chunk
    const int slot = l & 3;    // staging: stored 16B slot within 64B row
    const int kg   = l >> 4;   // fragment: k-group 0..3 (16 int8 each)
    const int lr   = l & 15;   // fragment: row/col within 16

    for (int kt = 0; kt < NKT; ++kt) {
        __syncthreads();   // previous iteration's ds_reads done before overwrite
#pragma unroll
        for (int r = 0; r < 2; ++r) {
            const int chunk = r * 4 + w;          // 0..7, wave-uniform
            const int row = chunk * 16 + crow;    // 0..127
            const int ss = slot ^ ((row >> 1) & 3);
            const signed char* ga = A + (size_t)(brow * 128 + row) * KPAD
                                      + (size_t)kt * 64 + ss * 16;
            __builtin_amdgcn_global_load_lds(
                (const __attribute__((address_space(1))) void*)ga,
                (__attribute__((address_space(3))) void*)(As + chunk * 1024),
                16, 0, 0);
            const signed char* gb = Bq + (size_t)(bcol * 128 + row) * KPAD
                                       + (size_t)kt * 64 + ss * 16;
            __builtin_amdgcn_global_load_lds(
                (const __attribute__((address_space(1))) void*)gb,
                (__attribute__((address_space(3))) void*)(Bs + chunk * 1024),
                16, 0, 0);
        }
        __syncthreads();   // vmcnt(0) drain before fragment reads

        i32x4 af[4], bf[4];
#pragma unroll
        for (int m = 0; m < 4; ++m) {
            const int ar = wrow * 64 + m * 16 + lr;
            const int s = kg ^ ((ar >> 1) & 3);
            af[m] = *reinterpret_cast<const i32x4*>(As + ar * 64 + s * 16);
        }
#pragma unroll
        for (int n = 0; n < 4; ++n) {
            const int br = wcol * 64 + n * 16 + lr;
            const int s = kg ^ ((br >> 1) & 3);
            bf[n] = *reinterpret_cast<const i32x4*>(Bs + br * 64 + s * 16);
        }
#pragma unroll
        for (int m = 0; m < 4; ++m)
#pragma unroll
            for (int n = 0; n < 4; ++n)
                acc[m][n] = __builtin_amdgcn_mfma_i32_16x16x64_i8(
                    af[m], bf[n], acc[m][n], 0, 0, 0);
    }

    // epilogue: scale + noise, fused write
    const float sc = 1.0f / (31.75f * 127.0f);
#pragma unroll
    for (int m = 0; m < 4; ++m) {
        const int gr0 = brow * 128 + wrow * 64 + m * 16 + (kg << 2);
#pragma unroll
        for (int n = 0; n < 4; ++n) {
            const int gc = bcol * 128 + wcol * 64 + n * 16 + lr;
#pragma unroll
            for (int j = 0; j < 4; ++j) {
                const size_t off = (size_t)(gr0 + j) * OUT_DIM + gc;
                out[off] = (float)acc[m][n][j] * sc + 0.01f * noise[off];
            }
        }
    }
}

extern "C" void kernel_launch(void* const* d_in, const int* in_sizes, int n_in,
                              void* d_out, int out_size, void* d_ws, size_t ws_size,
                              hipStream_t stream)
{
    const float* tensor  = (const float*)d_in[0];  // [4096][4096]
    const float* weights = (const float*)d_in[1];  // [4096][4096]
    const float* biases  = (const float*)d_in[2];  // [4096]
    const float* noise   = (const float*)d_in[3];  // [4096][4096]
    float* out = (float*)d_out;

    signed char* qx = (signed char*)d_ws;
    signed char* qw = qx + (size_t)B_DIM * KPAD;   // 17,039,360 B each

    const int qblocks = (B_DIM * C16 + 255) / 256; // 4160
    quant_kernel<<<qblocks, 256, 0, stream>>>(tensor, nullptr, qx,
                                              4.0f, 31.75f, B_DIM);
    quant_kernel<<<qblocks, 256, 0, stream>>>(weights, biases, qw,
                                              1.0f, 127.0f, OUT_DIM);
    gemm_i8_kernel<<<1024, 256, 0, stream>>>(qx, qw, noise, out);
}

// Round 4
// 271.221 us; speedup vs baseline: 1.2713x; 1.2713x over previous
//
#include <hip/hip_runtime.h>

typedef int i32x4 __attribute__((ext_vector_type(4)));

#define B_DIM   4096
#define IN_DIM  4096
#define OUT_DIM 4096
#define KPAD    4224        // 33 * 128; covers 4097 augmented K, zero-padded
#define NKT     33          // K-tiles of BK=128

// ---------------------------------------------------------------------------
// Coalesced quantize: one float4 per lane (lane-consecutive 16B loads),
// packed 4x int8 store. Covers cols 0..4095 of both matrices in one launch.
// ---------------------------------------------------------------------------
__global__ __launch_bounds__(256) void quant_main(
    const float* __restrict__ x, const float* __restrict__ wgt,
    signed char* __restrict__ qx, signed char* __restrict__ qw)
{
    const int PER = B_DIM * (IN_DIM / 4);
    int idx = blockIdx.x * 256 + threadIdx.x;
    const float* src; signed char* dst; float clip, scale; int i;
    if (idx < PER) { src = x;   dst = qx; clip = 4.0f; scale = 31.75f; i = idx; }
    else           { src = wgt; dst = qw; clip = 1.0f; scale = 127.0f; i = idx - PER; }
    const int row = i >> 10;          // 1024 float4 per 4096-col row
    const int c4  = i & 1023;
    float4 v = *reinterpret_cast<const float4*>(src + ((size_t)row << 12) + (c4 << 2));
    int o0 = (int)rintf(fminf(fmaxf(v.x, -clip), clip) * scale);
    int o1 = (int)rintf(fminf(fmaxf(v.y, -clip), clip) * scale);
    int o2 = (int)rintf(fminf(fmaxf(v.z, -clip), clip) * scale);
    int o3 = (int)rintf(fminf(fmaxf(v.w, -clip), clip) * scale);
    int packed = (o0 & 0xff) | ((o1 & 0xff) << 8) | ((o2 & 0xff) << 16) | ((o3 & 0xff) << 24);
    *reinterpret_cast<int*>(dst + (size_t)row * KPAD + (c4 << 2)) = packed;
}

// Pad region: cols 4096..4223 (128B/row). Byte 4096 = quantized aug value
// (1.0 for activations -> 32; clipped bias*127 for weights), rest zero.
__global__ __launch_bounds__(256) void quant_pad(
    const float* __restrict__ biases,
    signed char* __restrict__ qx, signed char* __restrict__ qw)
{
    int idx = blockIdx.x * 256 + threadIdx.x;   // 2 * 4096 * 8 threads
    const int which = idx >> 15;
    const int r = (idx >> 3) & 4095;
    const int c = idx & 7;
    signed char* q = which ? qw : qx;
    signed char o[16] __attribute__((aligned(16)));
#pragma unroll
    for (int j = 0; j < 16; ++j) o[j] = 0;
    if (c == 0) {
        float av = which ? fminf(fmaxf(biases[r], -1.0f), 1.0f) * 127.0f : 31.75f;
        o[0] = (signed char)(int)rintf(av);
    }
    *reinterpret_cast<i32x4*>(q + (size_t)r * KPAD + 4096 + c * 16) =
        *reinterpret_cast<const i32x4*>(o);
}

// ---------------------------------------------------------------------------
// 256x256 8-phase i8 GEMM (T2 swizzle + T3/T4 counted vmcnt + T5 setprio).
// BK=128 (2 K-slices of the 16x16x64 MFMA), 8 waves (2M x 4N), 512 threads,
// 128 KiB LDS (2 buffers x (A 32K + B 32K)). Per K-tile: 4 phases x 16 MFMA.
// Staging: B-halves of tile t+1 at phases 0/1; A (both halves) of tile t+2
// at phase 3; per-tile wait vmcnt(4) (never 0 in steady state) then barrier.
// Swizzle: physical 16B slot = logical slot ^ (row & 7); applied via
// pre-swizzled global source (linear global_load_lds dest) + swizzled ds_read.
// ---------------------------------------------------------------------------
#define FENCE() asm volatile("" ::: "memory")
#define BARRIER() do { FENCE(); __builtin_amdgcn_s_barrier(); FENCE(); } while (0)
#define WAITVM(N) asm volatile("s_waitcnt vmcnt(" #N ")" ::: "memory")
#define GLD16(g, lp) __builtin_amdgcn_global_load_lds( \
    (const __attribute__((address_space(1))) void*)(g), \
    (__attribute__((address_space(3))) void*)(lp), 16, 0, 0)

#define STAGE_A(bufi, t_) do { \
    const signed char* g_ = A + aoff0 + (size_t)(t_) * 128; \
    GLD16(g_,                      &As[bufi][0 * 8192 + w * 1024]); \
    GLD16(g_ + (size_t)64 * KPAD,  &As[bufi][1 * 8192 + w * 1024]); \
    GLD16(g_ + (size_t)128 * KPAD, &As[bufi][2 * 8192 + w * 1024]); \
    GLD16(g_ + (size_t)192 * KPAD, &As[bufi][3 * 8192 + w * 1024]); \
} while (0)

#define STAGE_BH(bufi, t_, h_) do { \
    const signed char* g_ = Bq + boff0 + (size_t)(t_) * 128 + (size_t)(h_) * 128 * KPAD; \
    GLD16(g_,                     &Bs[bufi][(h_) * 16384 + w * 1024]); \
    GLD16(g_ + (size_t)64 * KPAD, &Bs[bufi][(h_) * 16384 + 8192 + w * 1024]); \
} while (0)

#define MFMA_Q(mh, nh) do { \
    __builtin_amdgcn_s_setprio(1); \
    _Pragma("unroll") \
    for (int mi_ = 0; mi_ < 4; ++mi_) { \
        _Pragma("unroll") \
        for (int ni_ = 0; ni_ < 2; ++ni_) { \
            acc[(mh)*4+mi_][(nh)*2+ni_] = __builtin_amdgcn_mfma_i32_16x16x64_i8( \
                af[mi_][0], bf[(nh)*2+ni_][0], acc[(mh)*4+mi_][(nh)*2+ni_], 0, 0, 0); \
            acc[(mh)*4+mi_][(nh)*2+ni_] = __builtin_amdgcn_mfma_i32_16x16x64_i8( \
                af[mi_][1], bf[(nh)*2+ni_][1], acc[(mh)*4+mi_][(nh)*2+ni_], 0, 0, 0); \
        } \
    } \
    __builtin_amdgcn_s_setprio(0); \
} while (0)

#define TILE(t_, buf_, SB_, SA_, VMN_) do { \
    /* phase 0: read A[m0-3] + B[n0-1]; stage B-half0(t+1) */ \
    _Pragma("unroll") \
    for (int mi_ = 0; mi_ < 4; ++mi_) { \
        af[mi_][0] = *(const i32x4*)&As[buf_][arow0 + mi_ * 2048 + ca0]; \
        af[mi_][1] = *(const i32x4*)&As[buf_][arow0 + mi_ * 2048 + ca1]; \
    } \
    _Pragma("unroll") \
    for (int ni_ = 0; ni_ < 2; ++ni_) { \
        bf[ni_][0] = *(const i32x4*)&Bs[buf_][brow0 + ni_ * 2048 + ca0]; \
        bf[ni_][1] = *(const i32x4*)&Bs[buf_][brow0 + ni_ * 2048 + ca1]; \
    } \
    if (SB_) STAGE_BH((buf_) ^ 1, (t_) + 1, 0); \
    BARRIER(); \
    MFMA_Q(0, 0); \
    BARRIER(); \
    /* phase 1: read B[n2-3]; stage B-half1(t+1) */ \
    _Pragma("unroll") \
    for (int ni_ = 0; ni_ < 2; ++ni_) { \
        bf[2+ni_][0] = *(const i32x4*)&Bs[buf_][brow0 + (2+ni_) * 2048 + ca0]; \
        bf[2+ni_][1] = *(const i32x4*)&Bs[buf_][brow0 + (2+ni_) * 2048 + ca1]; \
    } \
    if (SB_) STAGE_BH((buf_) ^ 1, (t_) + 1, 1); \
    BARRIER(); \
    MFMA_Q(0, 1); \
    BARRIER(); \
    /* phase 2: read A[m4-7] */ \
    _Pragma("unroll") \
    for (int mi_ = 0; mi_ < 4; ++mi_) { \
        af[mi_][0] = *(const i32x4*)&As[buf_][arow0 + (4+mi_) * 2048 + ca0]; \
        af[mi_][1] = *(const i32x4*)&As[buf_][arow0 + (4+mi_) * 2048 + ca1]; \
    } \
    BARRIER(); \
    MFMA_Q(1, 0); \
    BARRIER(); \
    /* phase 3: stage A(t+2) into this buffer (its A reads are done) */ \
    if (SA_) STAGE_A(buf_, (t_) + 2); \
    MFMA_Q(1, 1); \
    WAITVM(VMN_);   /* own loads landed -> barrier makes it global */ \
    BARRIER(); \
} while (0)

__global__ __launch_bounds__(512, 2) void gemm_i8_kernel(
    const signed char* __restrict__ A,   // qx [B_DIM][KPAD]
    const signed char* __restrict__ Bq,  // qw [OUT_DIM][KPAD]
    const float* __restrict__ noise,
    float* __restrict__ out)
{
    __shared__ __align__(16) signed char As[2][256 * 128];
    __shared__ __align__(16) signed char Bs[2][256 * 128];

    const int tid = threadIdx.x;
    const int w = tid >> 6;
    const int l = tid & 63;
    const int wr = w >> 2;      // 0..1  (M)
    const int wc = w & 3;       // 0..3  (N)

    const int bid = blockIdx.x;               // 256 blocks, 256 % 8 == 0
    const int swz = (bid & 7) * 32 + (bid >> 3);
    const int brow = swz >> 4;                // 0..15
    const int bcol = swz & 15;                // 0..15

    // staging source offsets (fixed per thread; +t*128 per tile)
    const int srow = tid >> 3;                              // 0..63
    const int cswz = ((tid & 7) ^ (srow & 7)) << 4;         // pre-swizzled slot
    const size_t aoff0 = (size_t)(brow * 256 + srow) * KPAD + cswz;
    const size_t boff0 = (size_t)(bcol * 256 + srow) * KPAD + cswz;

    // fragment read offsets
    const int lr = l & 15;
    const int kg = l >> 4;
    const int sx = (lr & 7) << 4;
    const int ca0 = ((kg << 4)) ^ sx;         // k-slice 0 column bytes (swz)
    const int ca1 = (64 | (kg << 4)) ^ sx;    // k-slice 1
    const int arow0 = (wr * 128 + lr) * 128;  // lane's A row base (bytes)
    const int brow0 = (wc * 64 + lr) * 128;   // lane's B row base (bytes)

    i32x4 acc[8][4];
#pragma unroll
    for (int m = 0; m < 8; ++m)
#pragma unroll
        for (int n = 0; n < 4; ++n) acc[m][n] = (i32x4)(0);
    i32x4 af[4][2], bf[4][2];

    // prologue: tile0 fully + tile1 A; wait all of tile0 (leave tile1 A in flight)
    STAGE_A(0, 0);
    STAGE_BH(0, 0, 0);
    STAGE_BH(0, 0, 1);
    STAGE_A(1, 1);
    WAITVM(4);
    BARRIER();

    for (int t = 0; t < NKT - 2; ++t) {       // t = 0..30
        TILE(t, (t & 1), 1, 1, 4);
    }
    TILE(NKT - 2, ((NKT - 2) & 1), 1, 0, 0);  // stages B(32), drain
    TILE(NKT - 1, ((NKT - 1) & 1), 0, 0, 0);  // no staging

    // epilogue: scale + noise, fused
    const float sc = 1.0f / 4032.25f;         // 1/(31.75*127)
#pragma unroll
    for (int mi = 0; mi < 8; ++mi) {
        const int grow = brow * 256 + wr * 128 + mi * 16 + kg * 4;
#pragma unroll
        for (int ni = 0; ni < 4; ++ni) {
            const int gcol = bcol * 256 + wc * 64 + ni * 16 + lr;
#pragma unroll
            for (int j = 0; j < 4; ++j) {
                const size_t off = (size_t)(grow + j) * OUT_DIM + gcol;
                out[off] = (float)acc[mi][ni][j] * sc + 0.01f * noise[off];
            }
        }
    }
}

extern "C" void kernel_launch(void* const* d_in, const int* in_sizes, int n_in,
                              void* d_out, int out_size, void* d_ws, size_t ws_size,
                              hipStream_t stream)
{
    const float* tensor  = (const float*)d_in[0];
    const float* weights = (const float*)d_in[1];
    const float* biases  = (const float*)d_in[2];
    const float* noise   = (const float*)d_in[3];
    float* out = (float*)d_out;

    signed char* qx = (signed char*)d_ws;
    signed char* qw = qx + (size_t)B_DIM * KPAD;

    const int qblocks = (2 * B_DIM * (IN_DIM / 4)) / 256;   // 32768
    quant_main<<<qblocks, 256, 0, stream>>>(tensor, weights, qx, qw);
    quant_pad<<<(2 * B_DIM * 8) / 256, 256, 0, stream>>>(biases, qx, qw);
    gemm_i8_kernel<<<256, 512, 0, stream>>>(qx, qw, noise, out);
}

// Round 5
// 264.855 us; speedup vs baseline: 1.3019x; 1.0240x over previous
//
#include <hip/hip_runtime.h>

typedef int i32x4 __attribute__((ext_vector_type(4)));

#define B_DIM   4096
#define IN_DIM  4096
#define OUT_DIM 4096
#define NKT     32          // K-tiles of BK=128 over the 4096 real columns
// augmented column folded analytically: y = int_dot + 32*qb[o], qx_aug = 32

// ---------------------------------------------------------------------------
// Coalesced quantize: one float4 per lane, packed 4x int8 store, dense
// [4096][4096] i8 output. Last block (idx==QBLOCKS) quantizes biases -> qb.
// ---------------------------------------------------------------------------
#define QBLOCKS 32768
__global__ __launch_bounds__(256) void quant_main(
    const float* __restrict__ x, const float* __restrict__ wgt,
    const float* __restrict__ biases,
    signed char* __restrict__ qx, signed char* __restrict__ qw,
    signed char* __restrict__ qb)
{
    if (blockIdx.x == QBLOCKS) {        // bias path: 256 threads x 16 entries
        const int base = threadIdx.x * 16;
        signed char o[16] __attribute__((aligned(16)));
#pragma unroll
        for (int j = 0; j < 4; ++j) {
            float4 v = *reinterpret_cast<const float4*>(biases + base + j * 4);
            o[j*4+0] = (signed char)(int)rintf(fminf(fmaxf(v.x, -1.0f), 1.0f) * 127.0f);
            o[j*4+1] = (signed char)(int)rintf(fminf(fmaxf(v.y, -1.0f), 1.0f) * 127.0f);
            o[j*4+2] = (signed char)(int)rintf(fminf(fmaxf(v.z, -1.0f), 1.0f) * 127.0f);
            o[j*4+3] = (signed char)(int)rintf(fminf(fmaxf(v.w, -1.0f), 1.0f) * 127.0f);
        }
        *reinterpret_cast<i32x4*>(qb + base) = *reinterpret_cast<const i32x4*>(o);
        return;
    }
    const int PER = B_DIM * (IN_DIM / 4);
    int idx = blockIdx.x * 256 + threadIdx.x;
    const float* src; signed char* dst; float clip, scale; int i;
    if (idx < PER) { src = x;   dst = qx; clip = 4.0f; scale = 31.75f; i = idx; }
    else           { src = wgt; dst = qw; clip = 1.0f; scale = 127.0f; i = idx - PER; }
    const int row = i >> 10;
    const int c4  = i & 1023;
    float4 v = *reinterpret_cast<const float4*>(src + ((size_t)row << 12) + (c4 << 2));
    int o0 = (int)rintf(fminf(fmaxf(v.x, -clip), clip) * scale);
    int o1 = (int)rintf(fminf(fmaxf(v.y, -clip), clip) * scale);
    int o2 = (int)rintf(fminf(fmaxf(v.z, -clip), clip) * scale);
    int o3 = (int)rintf(fminf(fmaxf(v.w, -clip), clip) * scale);
    int packed = (o0 & 0xff) | ((o1 & 0xff) << 8) | ((o2 & 0xff) << 16) | ((o3 & 0xff) << 24);
    *reinterpret_cast<int*>(dst + ((size_t)row << 12) + (c4 << 2)) = packed;
}

// ---------------------------------------------------------------------------
// 256x256 8-phase i8 GEMM (T2 swizzle + T3/T4 counted vmcnt + T5 setprio),
// with LDS-repacked fully-coalesced epilogue (noise + bias fused).
// ---------------------------------------------------------------------------
#define FENCE() asm volatile("" ::: "memory")
#define BARRIER() do { FENCE(); __builtin_amdgcn_s_barrier(); FENCE(); } while (0)
#define WAITVM(N) asm volatile("s_waitcnt vmcnt(" #N ")" ::: "memory")
#define GLD16(g, lp) __builtin_amdgcn_global_load_lds( \
    (const __attribute__((address_space(1))) void*)(g), \
    (__attribute__((address_space(3))) void*)(lp), 16, 0, 0)

#define ASP(bufi) (smem + (bufi) * 32768)
#define BSP(bufi) (smem + 65536 + (bufi) * 32768)

#define STAGE_A(bufi, t_) do { \
    const signed char* g_ = A + aoff0 + (size_t)(t_) * 128; \
    GLD16(g_,                          ASP(bufi) + 0 * 8192 + w * 1024); \
    GLD16(g_ + (size_t)64  * IN_DIM,   ASP(bufi) + 1 * 8192 + w * 1024); \
    GLD16(g_ + (size_t)128 * IN_DIM,   ASP(bufi) + 2 * 8192 + w * 1024); \
    GLD16(g_ + (size_t)192 * IN_DIM,   ASP(bufi) + 3 * 8192 + w * 1024); \
} while (0)

#define STAGE_BH(bufi, t_, h_) do { \
    const signed char* g_ = Bq + boff0 + (size_t)(t_) * 128 + (size_t)(h_) * 128 * IN_DIM; \
    GLD16(g_,                         BSP(bufi) + (h_) * 16384 + w * 1024); \
    GLD16(g_ + (size_t)64 * IN_DIM,   BSP(bufi) + (h_) * 16384 + 8192 + w * 1024); \
} while (0)

#define MFMA_Q(mh, nh) do { \
    __builtin_amdgcn_s_setprio(1); \
    _Pragma("unroll") \
    for (int mi_ = 0; mi_ < 4; ++mi_) { \
        _Pragma("unroll") \
        for (int ni_ = 0; ni_ < 2; ++ni_) { \
            acc[(mh)*4+mi_][(nh)*2+ni_] = __builtin_amdgcn_mfma_i32_16x16x64_i8( \
                af[mi_][0], bf[(nh)*2+ni_][0], acc[(mh)*4+mi_][(nh)*2+ni_], 0, 0, 0); \
            acc[(mh)*4+mi_][(nh)*2+ni_] = __builtin_amdgcn_mfma_i32_16x16x64_i8( \
                af[mi_][1], bf[(nh)*2+ni_][1], acc[(mh)*4+mi_][(nh)*2+ni_], 0, 0, 0); \
        } \
    } \
    __builtin_amdgcn_s_setprio(0); \
} while (0)

#define TILE(t_, buf_, SB_, SA_, VMN_) do { \
    /* phase 0: read A[m0-3]+B[n0-1]; stage B-half0(t+1) */ \
    _Pragma("unroll") \
    for (int mi_ = 0; mi_ < 4; ++mi_) { \
        af[mi_][0] = *(const i32x4*)(ASP(buf_) + arow0 + mi_ * 2048 + ca0); \
        af[mi_][1] = *(const i32x4*)(ASP(buf_) + arow0 + mi_ * 2048 + ca1); \
    } \
    _Pragma("unroll") \
    for (int ni_ = 0; ni_ < 2; ++ni_) { \
        bf[ni_][0] = *(const i32x4*)(BSP(buf_) + brow0 + ni_ * 2048 + ca0); \
        bf[ni_][1] = *(const i32x4*)(BSP(buf_) + brow0 + ni_ * 2048 + ca1); \
    } \
    if (SB_) STAGE_BH((buf_) ^ 1, (t_) + 1, 0); \
    BARRIER(); \
    MFMA_Q(0, 0); \
    BARRIER(); \
    /* phase 1: read B[n2-3]; stage B-half1(t+1) */ \
    _Pragma("unroll") \
    for (int ni_ = 0; ni_ < 2; ++ni_) { \
        bf[2+ni_][0] = *(const i32x4*)(BSP(buf_) + brow0 + (2+ni_) * 2048 + ca0); \
        bf[2+ni_][1] = *(const i32x4*)(BSP(buf_) + brow0 + (2+ni_) * 2048 + ca1); \
    } \
    if (SB_) STAGE_BH((buf_) ^ 1, (t_) + 1, 1); \
    BARRIER(); \
    MFMA_Q(0, 1); \
    BARRIER(); \
    /* phase 2: read A[m4-7] */ \
    _Pragma("unroll") \
    for (int mi_ = 0; mi_ < 4; ++mi_) { \
        af[mi_][0] = *(const i32x4*)(ASP(buf_) + arow0 + (4+mi_) * 2048 + ca0); \
        af[mi_][1] = *(const i32x4*)(ASP(buf_) + arow0 + (4+mi_) * 2048 + ca1); \
    } \
    BARRIER(); \
    MFMA_Q(1, 0); \
    BARRIER(); \
    /* phase 3: stage A(t+2) into this buffer */ \
    if (SA_) STAGE_A(buf_, (t_) + 2); \
    MFMA_Q(1, 1); \
    WAITVM(VMN_); \
    BARRIER(); \
} while (0)

__global__ __launch_bounds__(512, 2) void gemm_i8_kernel(
    const signed char* __restrict__ A,   // qx [4096][4096]
    const signed char* __restrict__ Bq,  // qw [4096][4096]
    const signed char* __restrict__ Qb,  // qb [4096]
    const float* __restrict__ noise,
    float* __restrict__ out)
{
    __shared__ __align__(16) signed char smem[131072]; // 2x(A 32K) + 2x(B 32K)

    const int tid = threadIdx.x;
    const int w = tid >> 6;
    const int l = tid & 63;
    const int wr = w >> 2;      // 0..1  (M)
    const int wc = w & 3;       // 0..3  (N)

    const int bid = blockIdx.x;               // 256 blocks, %8==0
    const int swz = (bid & 7) * 32 + (bid >> 3);
    const int brow = swz >> 4;                // 0..15
    const int bcol = swz & 15;                // 0..15

    const int srow = tid >> 3;                              // 0..63
    const int cswz = ((tid & 7) ^ (srow & 7)) << 4;         // pre-swizzled slot
    const size_t aoff0 = (size_t)(brow * 256 + srow) * IN_DIM + cswz;
    const size_t boff0 = (size_t)(bcol * 256 + srow) * IN_DIM + cswz;

    const int lr = l & 15;
    const int kg = l >> 4;
    const int sx = (lr & 7) << 4;
    const int ca0 = ((kg << 4)) ^ sx;
    const int ca1 = (64 | (kg << 4)) ^ sx;
    const int arow0 = (wr * 128 + lr) * 128;
    const int brow0 = (wc * 64 + lr) * 128;

    i32x4 acc[8][4];
#pragma unroll
    for (int m = 0; m < 8; ++m)
#pragma unroll
        for (int n = 0; n < 4; ++n) acc[m][n] = (i32x4)(0);
    i32x4 af[4][2], bf[4][2];

    STAGE_A(0, 0);
    STAGE_BH(0, 0, 0);
    STAGE_BH(0, 0, 1);
    STAGE_A(1, 1);
    WAITVM(4);
    BARRIER();

    for (int t = 0; t < NKT - 2; ++t) {       // t = 0..29
        TILE(t, (t & 1), 1, 1, 4);
    }
    TILE(NKT - 2, 0, 1, 0, 0);                // stages B(31), full drain
    TILE(NKT - 1, 1, 0, 0, 0);                // no staging

    // ---- epilogue: LDS repack -> fully coalesced noise+bias+store ----
    const float sc = 1.0f / 4032.25f;         // 1/(31.75*127)
    float* eps = (float*)smem;                // [128][256] f32 = 128 KiB
#pragma unroll
    for (int r = 0; r < 2; ++r) {
        __syncthreads();                      // LDS free / prev round consumed
        if (wr == r) {
#pragma unroll
            for (int mi = 0; mi < 8; ++mi) {
                const int lrow = mi * 16 + (kg << 2);
#pragma unroll
                for (int ni = 0; ni < 4; ++ni) {
                    const int lcol = wc * 64 + ni * 16 + lr;
#pragma unroll
                    for (int j = 0; j < 4; ++j)
                        ((int*)eps)[(lrow + j) * 256 + lcol] = acc[mi][ni][j];
                }
            }
        }
        __syncthreads();                      // writes visible
#pragma unroll
        for (int i = 0; i < 16; ++i) {
            const int idx = i * 512 + tid;    // 16B chunk id, 0..8191
            const int row = idx >> 6;         // 0..127 (one full row per wave)
            const int c16 = idx & 63;         // 16B chunk within row
            int4 a4 = *reinterpret_cast<const int4*>((const char*)eps + row * 1024 + c16 * 16);
            int qb4 = *reinterpret_cast<const int*>(Qb + bcol * 256 + c16 * 4);
            const size_t off = (size_t)(brow * 256 + r * 128 + row) * OUT_DIM
                             + bcol * 256 + c16 * 4;
            float4 nz = *reinterpret_cast<const float4*>(noise + off);
            float4 o;
            o.x = (float)(a4.x + 32 * (int)(signed char)(qb4      )) * sc + 0.01f * nz.x;
            o.y = (float)(a4.y + 32 * (int)(signed char)(qb4 >>  8)) * sc + 0.01f * nz.y;
            o.z = (float)(a4.z + 32 * (int)(signed char)(qb4 >> 16)) * sc + 0.01f * nz.z;
            o.w = (float)(a4.w + 32 * (int)(signed char)(qb4 >> 24)) * sc + 0.01f * nz.w;
            *reinterpret_cast<float4*>(out + off) = o;
        }
    }
}

extern "C" void kernel_launch(void* const* d_in, const int* in_sizes, int n_in,
                              void* d_out, int out_size, void* d_ws, size_t ws_size,
                              hipStream_t stream)
{
    const float* tensor  = (const float*)d_in[0];
    const float* weights = (const float*)d_in[1];
    const float* biases  = (const float*)d_in[2];
    const float* noise   = (const float*)d_in[3];
    float* out = (float*)d_out;

    signed char* qx = (signed char*)d_ws;                       // 16 MiB
    signed char* qw = qx + (size_t)B_DIM * IN_DIM;              // 16 MiB
    signed char* qb = qw + (size_t)OUT_DIM * IN_DIM;            // 4 KiB

    quant_main<<<QBLOCKS + 1, 256, 0, stream>>>(tensor, weights, biases, qx, qw, qb);
    gemm_i8_kernel<<<256, 512, 0, stream>>>(qx, qw, qb, noise, out);
}